// Round 4
// baseline (8048.713 us; speedup 1.0000x reference)
//
#include <hip/hip_runtime.h>

#define B_ 64
#define T_ 4096
#define IN_ 128
#define H_ 256
#define TPB 512

using u64 = unsigned long long;

static constexpr size_t HBUF_U64 = 2ull * B_ * H_;   // u64 per buffer (256 KiB)
static constexpr size_t SLOW_OFF = HBUF_U64;         // slow mirror offset, u64 units

__device__ __forceinline__ float rdlane_f(float v, int k) {
    return __builtin_bit_cast(float, __builtin_amdgcn_readlane(__builtin_bit_cast(int, v), k));
}
__device__ __forceinline__ float fast_rcp(float x) { return __builtin_amdgcn_rcpf(x); }
__device__ __forceinline__ float fast_sigmoid(float x) {
    return fast_rcp(1.0f + __expf(-x));
}
__device__ __forceinline__ float fast_tanh(float x) {
    float ax = fabsf(x);
    float e  = __expf(-2.0f * ax);
    float t  = (1.0f - e) * fast_rcp(1.0f + e);
    return copysignf(t, x);
}
__device__ __forceinline__ u64 ld_agent(const u64* p) {
    return __hip_atomic_load(p, __ATOMIC_RELAXED, __HIP_MEMORY_SCOPE_AGENT);
}
__device__ __forceinline__ void st_agent(u64* p, u64 v) {
    __hip_atomic_store(p, v, __ATOMIC_RELAXED, __HIP_MEMORY_SCOPE_AGENT);
}
// L2-coherent probe: sc0 bypasses L1, hits the XCD-shared L2.
__device__ __forceinline__ u64 ld_sc0(const u64* p) {
    u64 r;
    asm volatile("global_load_dwordx2 %0, %1, off sc0\n\ts_waitcnt vmcnt(0)"
                 : "=v"(r) : "v"(p) : "memory");
    return r;
}
// plain store: write-through L1 -> lands in this XCD's L2.
__device__ __forceinline__ void st_plain(u64* p, u64 v) {
    asm volatile("global_store_dwordx2 %0, %1, off" :: "v"(p), "v"(v) : "memory");
}

__global__ __launch_bounds__(TPB, 2) void lstm_persist(
    const float* __restrict__ x,      // [B,T,IN]
    const float* __restrict__ W_ih,   // [1024,128]
    const float* __restrict__ W_hh,   // [1024,256]
    const float* __restrict__ b_ih,
    const float* __restrict__ b_hh,
    const float* __restrict__ fc_w,   // [128,256]
    const float* __restrict__ fc_b,   // [128]
    float* __restrict__ out,          // [B,128]
    u64* hb)                          // fast [2][B][256] + slow mirror at SLOW_OFF
{
    const int blk  = blockIdx.x;               // 256 blocks
    const int xcd  = blk & 7;                  // colocate a batch's 4 slices per XCD
    const int m    = blk >> 3;
    const int s    = m & 3;                    // h-slice this block PRODUCES
    const int b    = ((m >> 2) << 3) | xcd;    // batch
    const int tid  = threadIdx.x;
    const int lane = tid & 63;
    const int wave = tid >> 6;
    const int chunk = wave & 3;                // h-chunk this wave CONSUMES
    const int sub   = wave >> 2;               // 32-wide K sub-chunk
    const bool is_upd = (wave == s);           // producer wave: own chunk in registers

    const int row_base = s * 64 + lane;
    const int k_hh = chunk * 64 + sub * 32;
    const int k_ih = chunk * 32 + sub * 16;

    // --- persistent weights: 4 rows x 32 K (hh) + 4 rows x 16 K (ih) ---
    float w_hh[4][32];
    #pragma unroll
    for (int g = 0; g < 4; ++g) {
        const float4* src = (const float4*)(W_hh + (size_t)(g * 256 + row_base) * H_ + k_hh);
        #pragma unroll
        for (int q = 0; q < 8; ++q) {
            const float4 v = src[q];
            w_hh[g][q*4+0] = v.x; w_hh[g][q*4+1] = v.y;
            w_hh[g][q*4+2] = v.z; w_hh[g][q*4+3] = v.w;
        }
    }
    float w_ih[4][16];
    #pragma unroll
    for (int g = 0; g < 4; ++g) {
        const float4* src = (const float4*)(W_ih + (size_t)(g * 256 + row_base) * IN_ + k_ih);
        #pragma unroll
        for (int q = 0; q < 4; ++q) {
            const float4 v = src[q];
            w_ih[g][q*4+0] = v.x; w_ih[g][q*4+1] = v.y;
            w_ih[g][q*4+2] = v.z; w_ih[g][q*4+3] = v.w;
        }
    }
    float bias_[4] = {0.f, 0.f, 0.f, 0.f};
    if (is_upd) {
        #pragma unroll
        for (int g = 0; g < 4; ++g)
            bias_[g] = b_ih[g * 256 + row_base] + b_hh[g * 256 + row_base];
    }

    __shared__ float part[2][8][4][64];   // [parity][wave][gate][h-idx]

    float h_own = 0.0f, c_own = 0.0f;

    const float* xb = x + (size_t)b * T_ * IN_;
    float vx = xb[k_ih + (lane & 15)];

    u64* const hb_b  = hb + (size_t)b * 256;                       // + parity*B_*256
    const u64* const poll0 = hb + (size_t)b * 256 + chunk * 64 + lane;

    for (int t = 0; t < T_; ++t) {
        const int p  = t & 1;
        const int pn = p ^ 1;
        float a0 = 0.f, a1 = 0.f, a2 = 0.f, a3 = 0.f;

        const u64* pp_fast = poll0 + (size_t)p * (B_ * 256);
        const u64* pp_slow = pp_fast + SLOW_OFF;

        // speculative agent probe, hoisted so its latency hides under ih FMAs
        u64 vspec = 0;
        if (!is_upd) vspec = ld_agent(pp_slow);

        const int tn = (t + 1 < T_) ? t + 1 : t;
        const float vxn = xb[(size_t)tn * IN_ + k_ih + (lane & 15)];   // prefetch

        // ih contribution — independent of h
        #pragma unroll
        for (int k = 0; k < 16; ++k) {
            const float xv = rdlane_f(vx, k);
            a0 = fmaf(xv, w_ih[0][k], a0);
            a1 = fmaf(xv, w_ih[1][k], a1);
            a2 = fmaf(xv, w_ih[2][k], a2);
            a3 = fmaf(xv, w_ih[3][k], a3);
        }
        vx = vxn;

        // obtain this wave's h-chunk
        float vh;
        if (is_upd) {
            vh = h_own;                         // register fast path
        } else {
            u64 v = vspec;
            const unsigned tv = (unsigned)t;
            if ((unsigned)(v >> 32) < tv) {
                int tries = 0;
                for (;;) {
                    v = ld_sc0(pp_fast);        // L2-coherent fast path
                    if ((unsigned)(v >> 32) >= tv) break;
                    if (++tries >= 8) {         // cross-XCD safety escalation
                        u64 w = ld_agent(pp_slow);
                        if ((unsigned)(w >> 32) >= tv) { v = w; break; }
                    }
                }
            }
            vh = __builtin_bit_cast(float, (unsigned)v);
        }

        // hh FMAs: 1 readlane + 4 fmac per k
        if (sub == 0) {
            #pragma unroll
            for (int k = 0; k < 32; ++k) {
                const float hv = rdlane_f(vh, k);
                a0 = fmaf(hv, w_hh[0][k], a0);
                a1 = fmaf(hv, w_hh[1][k], a1);
                a2 = fmaf(hv, w_hh[2][k], a2);
                a3 = fmaf(hv, w_hh[3][k], a3);
            }
        } else {
            #pragma unroll
            for (int k = 0; k < 32; ++k) {
                const float hv = rdlane_f(vh, 32 + k);
                a0 = fmaf(hv, w_hh[0][k], a0);
                a1 = fmaf(hv, w_hh[1][k], a1);
                a2 = fmaf(hv, w_hh[2][k], a2);
                a3 = fmaf(hv, w_hh[3][k], a3);
            }
        }

        part[p][wave][0][lane] = a0;
        part[p][wave][1][lane] = a1;
        part[p][wave][2][lane] = a2;
        part[p][wave][3][lane] = a3;
        __syncthreads();

        if (is_upd) {
            float gi = bias_[0], gf = bias_[1], gg = bias_[2], go = bias_[3];
            #pragma unroll
            for (int pc = 0; pc < 8; ++pc) {
                gi += part[p][pc][0][lane];
                gf += part[p][pc][1][lane];
                gg += part[p][pc][2][lane];
                go += part[p][pc][3][lane];
            }
            const float i_ = fast_sigmoid(gi);
            const float f_ = fast_sigmoid(gf);
            const float g_ = fast_tanh(gg);
            const float o_ = fast_sigmoid(go);
            c_own = fmaf(f_, c_own, i_ * g_);
            h_own = o_ * fast_tanh(c_own);
            const u64 pk = ((u64)(unsigned)(t + 1) << 32)
                         | (u64)__builtin_bit_cast(unsigned, h_own);
            u64* dst = hb_b + (size_t)pn * (B_ * 256) + s * 64 + lane;
            st_plain(dst, pk);                  // fast: XCD-local L2
            st_agent(dst + SLOW_OFF, pk);       // slow mirror: device-visible
        }
    }

    // ---- final FC: out[b, 32s .. 32s+32) ---- (reads slow mirror, agent-safe)
    const u64* hT = hb + SLOW_OFF + (size_t)(T_ & 1) * (B_ * 256) + (size_t)b * 256;
    const int c = s * 32 + (tid >> 4);
    const int q = tid & 15;
    float pacc = 0.0f;
    #pragma unroll
    for (int e = 0; e < 16; ++e) {
        u64 v;
        do { v = ld_agent(hT + q * 16 + e); } while ((unsigned)(v >> 32) < (unsigned)T_);
        pacc = fmaf(fc_w[(size_t)c * H_ + q * 16 + e],
                    __builtin_bit_cast(float, (unsigned)v), pacc);
    }
    pacc += __shfl_xor(pacc, 1);
    pacc += __shfl_xor(pacc, 2);
    pacc += __shfl_xor(pacc, 4);
    pacc += __shfl_xor(pacc, 8);
    if (q == 0) out[(size_t)b * 128 + c] = pacc + fc_b[c];
}

extern "C" void kernel_launch(void* const* d_in, const int* in_sizes, int n_in,
                              void* d_out, int out_size, void* d_ws, size_t ws_size,
                              hipStream_t stream) {
    const float* x    = (const float*)d_in[0];
    const float* W_ih = (const float*)d_in[1];
    const float* W_hh = (const float*)d_in[2];
    const float* b_ih = (const float*)d_in[3];
    const float* b_hh = (const float*)d_in[4];
    const float* fc_w = (const float*)d_in[5];
    const float* fc_b = (const float*)d_in[6];
    float* out = (float*)d_out;

    u64* hb = (u64*)d_ws;
    // {ver=0, h=0.0f} everywhere == correct initial state for both buffers
    hipMemsetAsync(d_ws, 0, 2ull * HBUF_U64 * sizeof(u64), stream);

    lstm_persist<<<B_ * 4, TPB, 0, stream>>>(x, W_ih, W_hh, b_ih, b_hh, fc_w, fc_b,
                                             out, hb);
}

// Round 5
// 6603.290 us; speedup vs baseline: 1.2189x; 1.2189x over previous
//
#include <hip/hip_runtime.h>

#define B_ 64
#define T_ 4096
#define IN_ 128
#define H_ 256
#define TPB 512

using u64 = unsigned long long;

static constexpr int HB_STRIDE = B_ * H_;              // u64 per parity buffer
static constexpr size_t HB_BYTES = 2ull * HB_STRIDE * sizeof(u64);

__device__ __forceinline__ float rdlane_f(float v, int k) {
    return __builtin_bit_cast(float, __builtin_amdgcn_readlane(__builtin_bit_cast(int, v), k));
}
__device__ __forceinline__ float fast_rcp(float x) { return __builtin_amdgcn_rcpf(x); }
__device__ __forceinline__ float fast_sigmoid(float x) {
    return fast_rcp(1.0f + __expf(-x));
}
__device__ __forceinline__ float fast_tanh(float x) {
    float ax = fabsf(x);
    float e  = __expf(-2.0f * ax);
    float t  = (1.0f - e) * fast_rcp(1.0f + e);
    return copysignf(t, x);
}
__device__ __forceinline__ u64 ld_agent(const u64* p) {
    return __hip_atomic_load(p, __ATOMIC_RELAXED, __HIP_MEMORY_SCOPE_AGENT);
}
__device__ __forceinline__ void st_agent(u64* p, u64 v) {
    __hip_atomic_store(p, v, __ATOMIC_RELAXED, __HIP_MEMORY_SCOPE_AGENT);
}
// barrier that drains LDS ops only — leaves global loads/stores in flight
__device__ __forceinline__ void barrier_lgkm() {
    asm volatile("s_waitcnt lgkmcnt(0)" ::: "memory");
    __builtin_amdgcn_s_barrier();
}

__global__ __launch_bounds__(TPB, 2) void lstm_persist(
    const float* __restrict__ x,      // [B,T,IN]
    const float* __restrict__ W_ih,   // [1024,128]
    const float* __restrict__ W_hh,   // [1024,256]
    const float* __restrict__ b_ih,
    const float* __restrict__ b_hh,
    const float* __restrict__ fc_w,   // [128,256]
    const float* __restrict__ fc_b,   // [128]
    float* __restrict__ out,          // [B,128]
    u64* hb)                          // [2][B][256] packed {ver<<32 | f32(h)}
{
    const int blk  = blockIdx.x;               // 256 blocks
    const int xcd  = blk & 7;                  // colocate a batch's 4 slices (heuristic)
    const int m    = blk >> 3;
    const int s    = m & 3;                    // h-slice this block PRODUCES
    const int b    = ((m >> 2) << 3) | xcd;    // batch
    const int tid  = threadIdx.x;
    const int lane = tid & 63;
    const int wave = tid >> 6;
    const int chunk = wave & 3;                // h-chunk this wave CONSUMES
    const int sub   = wave >> 2;               // 32-wide K sub-chunk
    const bool is_upd = (chunk == s && sub == 0);

    const int row_base = s * 64 + lane;
    const int k_hh = chunk * 64 + sub * 32;
    const int k_ih = chunk * 32 + sub * 16;

    // --- persistent weights: 4 rows x 32 K (hh) + 4 rows x 16 K (ih) ---
    float w_hh[4][32];
    #pragma unroll
    for (int g = 0; g < 4; ++g) {
        const float4* src = (const float4*)(W_hh + (size_t)(g * 256 + row_base) * H_ + k_hh);
        #pragma unroll
        for (int q = 0; q < 8; ++q) {
            const float4 v = src[q];
            w_hh[g][q*4+0] = v.x; w_hh[g][q*4+1] = v.y;
            w_hh[g][q*4+2] = v.z; w_hh[g][q*4+3] = v.w;
        }
    }
    float w_ih[4][16];
    #pragma unroll
    for (int g = 0; g < 4; ++g) {
        const float4* src = (const float4*)(W_ih + (size_t)(g * 256 + row_base) * IN_ + k_ih);
        #pragma unroll
        for (int q = 0; q < 4; ++q) {
            const float4 v = src[q];
            w_ih[g][q*4+0] = v.x; w_ih[g][q*4+1] = v.y;
            w_ih[g][q*4+2] = v.z; w_ih[g][q*4+3] = v.w;
        }
    }
    float bias_[4] = {0.f, 0.f, 0.f, 0.f};
    if (is_upd) {
        #pragma unroll
        for (int g = 0; g < 4; ++g)
            bias_[g] = b_ih[g * 256 + row_base] + b_hh[g * 256 + row_base];
    }

    __shared__ float part[2][4][8][64];   // [parity][gate][wave][lane]

    float h_own = 0.0f, c_own = 0.0f;     // producer wave state (lane l <-> h[s*64+l])

    const float* xb = x + (size_t)b * T_ * IN_;
    float vx0 = xb[k_ih + (lane & 15)];            // x(0)
    float vx1 = xb[IN_ + k_ih + (lane & 15)];      // x(1)

    u64* const hstore = hb + (size_t)b * H_ + s * 64 + lane;          // + parity*HB_STRIDE
    const u64* const poll0 = hb + (size_t)b * H_ + chunk * 64 + lane; // + parity*HB_STRIDE

    auto step = [&](const int t, const int p, const float vx, float& vx_slot) {
        const int pn = p ^ 1;
        const u64* pp = poll0 + (size_t)p * HB_STRIDE;

        // (A) speculative early probe — latency hides under ih FMAs
        u64 vspec = 0;
        if (!is_upd) vspec = ld_agent(pp);

        // (B) ih contribution (h-independent)
        float a0 = bias_[0], a1 = bias_[1], a2 = bias_[2], a3 = bias_[3];
        #pragma unroll
        for (int k = 0; k < 16; ++k) {
            const float xv = rdlane_f(vx, k);
            a0 = fmaf(xv, w_ih[0][k], a0);
            a1 = fmaf(xv, w_ih[1][k], a1);
            a2 = fmaf(xv, w_ih[2][k], a2);
            a3 = fmaf(xv, w_ih[3][k], a3);
        }

        // (C) obtain this wave's h-chunk
        float vh;
        if (is_upd) {
            vh = h_own;                            // register fast path
        } else {
            u64 v = vspec;
            const unsigned tv = (unsigned)t;
            if ((unsigned)(v >> 32) < tv) {
                // dual-chain spin: two outstanding loads, ~2x sampling rate
                u64 vA = ld_agent(pp);
                u64 vB = ld_agent(pp);
                for (;;) {
                    if ((unsigned)(vA >> 32) >= tv) { v = vA; break; }
                    vA = ld_agent(pp);
                    if ((unsigned)(vB >> 32) >= tv) { v = vB; break; }
                    vB = ld_agent(pp);
                }
            }
            vh = __builtin_bit_cast(float, (unsigned)v);
        }

        // (D) x prefetch for t+2 — issued after all poll waits, 2 steps of slack
        {
            const int tf = (t + 2 < T_) ? (t + 2) : (T_ - 1);
            vx_slot = xb[(size_t)tf * IN_ + k_ih + (lane & 15)];
        }

        // (E) hh FMAs: 1 readlane + 4 fmac per k
        if (sub == 0) {
            #pragma unroll
            for (int k = 0; k < 32; ++k) {
                const float hv = rdlane_f(vh, k);
                a0 = fmaf(hv, w_hh[0][k], a0);
                a1 = fmaf(hv, w_hh[1][k], a1);
                a2 = fmaf(hv, w_hh[2][k], a2);
                a3 = fmaf(hv, w_hh[3][k], a3);
            }
        } else {
            #pragma unroll
            for (int k = 0; k < 32; ++k) {
                const float hv = rdlane_f(vh, 32 + k);
                a0 = fmaf(hv, w_hh[0][k], a0);
                a1 = fmaf(hv, w_hh[1][k], a1);
                a2 = fmaf(hv, w_hh[2][k], a2);
                a3 = fmaf(hv, w_hh[3][k], a3);
            }
        }

        // (F) partials to LDS (conflict-free: consecutive lanes -> consecutive banks)
        part[p][0][wave][lane] = a0;
        part[p][1][wave][lane] = a1;
        part[p][2][wave][lane] = a2;
        part[p][3][wave][lane] = a3;

        // (G) LDS-only barrier: global loads/stores stay in flight
        barrier_lgkm();

        // (H) producer: reduce + cell update + publish
        if (is_upd) {
            float gi = 0.f, gf = 0.f, gg = 0.f, go = 0.f;
            #pragma unroll
            for (int w = 0; w < 8; ++w) {
                gi += part[p][0][w][lane];
                gf += part[p][1][w][lane];
                gg += part[p][2][w][lane];
                go += part[p][3][w][lane];
            }
            const float i_ = fast_sigmoid(gi);
            const float f_ = fast_sigmoid(gf);
            const float g_ = fast_tanh(gg);
            const float o_ = fast_sigmoid(go);
            c_own = fmaf(f_, c_own, i_ * g_);
            h_own = o_ * fast_tanh(c_own);
            const u64 pk = ((u64)(unsigned)(t + 1) << 32)
                         | (u64)__builtin_bit_cast(unsigned, h_own);
            st_agent(hstore + (size_t)pn * HB_STRIDE, pk);
        }
        // part[] is parity-double-buffered; no second barrier needed
    };

    for (int t = 0; t < T_; t += 2) {
        step(t,     0, vx0, vx0);
        step(t + 1, 1, vx1, vx1);
    }

    // ---- final FC: out[b, 32s .. 32s+32) ----
    const u64* hT = hb + (size_t)(T_ & 1) * HB_STRIDE + (size_t)b * H_;
    const int c = s * 32 + (tid >> 4);
    const int q = tid & 15;
    float pacc = 0.0f;
    #pragma unroll
    for (int e = 0; e < 16; ++e) {
        u64 v;
        do { v = ld_agent(hT + q * 16 + e); } while ((unsigned)(v >> 32) < (unsigned)T_);
        pacc = fmaf(fc_w[(size_t)c * H_ + q * 16 + e],
                    __builtin_bit_cast(float, (unsigned)v), pacc);
    }
    pacc += __shfl_xor(pacc, 1);
    pacc += __shfl_xor(pacc, 2);
    pacc += __shfl_xor(pacc, 4);
    pacc += __shfl_xor(pacc, 8);
    if (q == 0) out[(size_t)b * 128 + c] = pacc + fc_b[c];
}

extern "C" void kernel_launch(void* const* d_in, const int* in_sizes, int n_in,
                              void* d_out, int out_size, void* d_ws, size_t ws_size,
                              hipStream_t stream) {
    const float* x    = (const float*)d_in[0];
    const float* W_ih = (const float*)d_in[1];
    const float* W_hh = (const float*)d_in[2];
    const float* b_ih = (const float*)d_in[3];
    const float* b_hh = (const float*)d_in[4];
    const float* fc_w = (const float*)d_in[5];
    const float* fc_b = (const float*)d_in[6];
    float* out = (float*)d_out;

    u64* hb = (u64*)d_ws;
    // {ver=0, h=0.0f} everywhere == correct initial state
    hipMemsetAsync(d_ws, 0, HB_BYTES, stream);

    lstm_persist<<<B_ * 4, TPB, 0, stream>>>(x, W_ih, W_hh, b_ih, b_hh, fc_w, fc_b,
                                             out, hb);
}